// Round 8
// baseline (2124.244 us; speedup 1.0000x reference)
//
#include <hip/hip_runtime.h>
#include <hip/hip_fp16.h>
#include <hip/hip_cooperative_groups.h>

namespace cg = cooperative_groups;

namespace {

constexpr int H = 1024, W = 1024, NB = 4;
constexpr int SH = 128, SW = 128;
constexpr float LAM = 0.24f;
constexpr float KK = 0.03f * 0.03f;
constexpr float DEPS_V = 0.1f;
constexpr float FFT_SCALE = 1.0f / (1024.0f * 1024.0f);  // ortho fwd+inv combined
constexpr int COL_LO = 256, NCOL = 512;  // masked columns k2 in [256,768); margin ~1.5e-3

__device__ __forceinline__ float2 cadd(float2 a, float2 b) { return make_float2(a.x + b.x, a.y + b.y); }
__device__ __forceinline__ float2 csub(float2 a, float2 b) { return make_float2(a.x - b.x, a.y - b.y); }
__device__ __forceinline__ float2 cmul(float2 a, float2 b) {
  return make_float2(a.x * b.x - a.y * b.y, a.x * b.y + a.y * b.x);
}
__device__ __forceinline__ int phys2(int e) { return e + (e >> 4); }

__device__ __forceinline__ float shift_from_bits(const unsigned* minp) {
  float mn = __uint_as_float(minp[0]);
  return (mn <= DEPS_V) ? DEPS_V : 0.0f;
}

// ---------------- min(source) via device-scope atomicMin on uint bits ----------------
__global__ void k_shift_min(const float* __restrict__ src, unsigned* __restrict__ minp) {
  int t = threadIdx.x;
  int b0 = blockIdx.x * 1024;
  float m = fminf(fminf(src[b0 + t], src[b0 + t + 256]),
                  fminf(src[b0 + t + 512], src[b0 + t + 768]));
  for (int o = 32; o > 0; o >>= 1) m = fminf(m, __shfl_xor(m, o));
  __shared__ float sm[4];
  if ((t & 63) == 0) sm[t >> 6] = m;
  __syncthreads();
  if (t == 0) {
    float mm = fminf(fminf(sm[0], sm[1]), fminf(sm[2], sm[3]));
    atomicMin(minp, __float_as_uint(mm));
  }
}

// ---------------- Stockham radix-4 1024-pt FFT (natural in -> natural out) ----------------
template <int NS, bool INV>
__device__ __forceinline__ void r4_butterfly(float2 v[4], int j, float2 r[4]) {
  if (NS > 1) {
    int p = j & (NS - 1);
    float sn, cs;
    sincospif((INV ? 1.0f : -1.0f) * (float)p * (1.0f / (float)(2 * NS)), &sn, &cs);
    float2 w1 = make_float2(cs, sn);
    float2 w2 = cmul(w1, w1);
    float2 w3 = cmul(w2, w1);
    v[1] = cmul(v[1], w1);
    v[2] = cmul(v[2], w2);
    v[3] = cmul(v[3], w3);
  }
  float2 a0 = cadd(v[0], v[2]), a2 = csub(v[0], v[2]);
  float2 a1 = cadd(v[1], v[3]), a3 = csub(v[1], v[3]);
  a3 = INV ? make_float2(-a3.y, a3.x) : make_float2(a3.y, -a3.x);
  r[0] = cadd(a0, a1);
  r[2] = csub(a0, a1);
  r[1] = cadd(a2, a3);
  r[3] = csub(a2, a3);
}

template <int NS, bool INV>
__device__ __forceinline__ void r4_stage_lds(float2 v[4], float2* dst, int j) {
  float2 r[4];
  r4_butterfly<NS, INV>(v, j, r);
  int p = j & (NS - 1);
  int base = ((j - p) << 2) + p;
#pragma unroll
  for (int k = 0; k < 4; ++k) dst[phys2(base + k * NS)] = r[k];
}

__device__ __forceinline__ void lds_load4(const float2* src, float2 v[4], int j) {
#pragma unroll
  for (int k = 0; k < 4; ++k) v[k] = src[phys2(j + k * 256)];
}

template <bool INV>
__device__ void fft1024(float2 v[4], float2* b0, float2* b1, int j) {
  r4_stage_lds<1, INV>(v, b0, j);
  __syncthreads();
  lds_load4(b0, v, j);
  r4_stage_lds<4, INV>(v, b1, j);
  __syncthreads();
  lds_load4(b1, v, j);
  r4_stage_lds<16, INV>(v, b0, j);
  __syncthreads();
  lds_load4(b0, v, j);
  r4_stage_lds<64, INV>(v, b1, j);
  __syncthreads();
  lds_load4(b1, v, j);
  float2 r[4];
  r4_butterfly<256, INV>(v, j, r);
#pragma unroll
  for (int k = 0; k < 4; ++k) v[k] = r[k];
}

// ---------------- forward row FFT, 2 real rows packed per complex transform ----------------
__global__ void k_rowfft_fwd(const float* __restrict__ guide, const float* __restrict__ ybic,
                             const unsigned* __restrict__ minp, float2* __restrict__ A) {
  __shared__ float2 b0[1088], b1[1088];
  int b = blockIdx.y, y0 = blockIdx.x * 2, j = threadIdx.x;
  float sh = shift_from_bits(minp);
  const float* g0 = guide + ((size_t)(b * 3 + 0) * H + y0) * W;
  const float* g1 = guide + ((size_t)(b * 3 + 1) * H + y0) * W;
  const float* g2 = guide + ((size_t)(b * 3 + 2) * H + y0) * W;
  const float* yb = ybic + ((size_t)b * H + y0) * W;
  float2 v[4];
#pragma unroll
  for (int k = 0; k < 4; ++k) {
    int x = j + k * 256;
    float s0 = g0[x] + g1[x] + g2[x] + (yb[x] + sh);
    float s1 = g0[x + W] + g1[x + W] + g2[x + W] + (yb[x + W] + sh);
    v[k] = make_float2(s0, s1);
  }
  fft1024<false>(v, b0, b1, j);
#pragma unroll
  for (int k = 0; k < 4; ++k) b0[phys2(j + k * 256)] = v[k];
  __syncthreads();
  float2* o0 = A + ((size_t)b * H + y0) * W;
  float2* o1 = o0 + W;
#pragma unroll
  for (int k = 0; k < 4; ++k) {
    int m = j + k * 256;
    float2 Zm = v[k];
    float2 Zc = b0[phys2((1024 - m) & 1023)];
    o0[m] = make_float2(0.5f * (Zm.x + Zc.x), 0.5f * (Zm.y - Zc.y));
    o1[m] = make_float2(0.5f * (Zm.y + Zc.y), 0.5f * (Zc.x - Zm.x));
  }
}

// ---------------- half-width transposes ----------------
__global__ void k_transpose_fwd(const float2* __restrict__ A, float2* __restrict__ Bc) {
  __shared__ float2 tile[32][33];
  int b = blockIdx.z;
  int c0 = blockIdx.x * 32, y0 = blockIdx.y * 32;
  const float2* ip = A + (size_t)b * H * W;
  float2* op = Bc + (size_t)b * NCOL * H;
#pragma unroll
  for (int k = 0; k < 4; ++k)
    tile[threadIdx.y + k * 8][threadIdx.x] =
        ip[(size_t)(y0 + threadIdx.y + k * 8) * W + (COL_LO + c0 + threadIdx.x)];
  __syncthreads();
#pragma unroll
  for (int k = 0; k < 4; ++k)
    op[(size_t)(c0 + threadIdx.y + k * 8) * H + (y0 + threadIdx.x)] =
        tile[threadIdx.x][threadIdx.y + k * 8];
}

__global__ void k_transpose_bwd(const float2* __restrict__ Bc, float2* __restrict__ A) {
  __shared__ float2 tile[32][33];
  int b = blockIdx.z;
  int c0 = blockIdx.x * 32, y0 = blockIdx.y * 32;
  const float2* ip = Bc + (size_t)b * NCOL * H;
  float2* op = A + (size_t)b * H * W;
#pragma unroll
  for (int k = 0; k < 4; ++k)
    tile[threadIdx.y + k * 8][threadIdx.x] =
        ip[(size_t)(c0 + threadIdx.y + k * 8) * H + (y0 + threadIdx.x)];
  __syncthreads();
#pragma unroll
  for (int k = 0; k < 4; ++k)
    op[(size_t)(y0 + threadIdx.y + k * 8) * W + (COL_LO + c0 + threadIdx.x)] =
        tile[threadIdx.x][threadIdx.y + k * 8];
}

// ---------------- column FFT + radial mask + inverse column FFT ----------------
__global__ void k_colfft_mask(float2* __restrict__ Bc) {
  __shared__ float2 b0[1088], b1[1088];
  int b = blockIdx.y, r = blockIdx.x, j = threadIdx.x;
  int k2 = COL_LO + r;
  double xj = -1.0 + 2.0 * (double)k2 / 1023.0;
  double xj2 = xj * xj;
  float2* row = Bc + ((size_t)b * NCOL + r) * H;
  float2 v[4];
#pragma unroll
  for (int k = 0; k < 4; ++k) v[k] = row[j + k * 256];
  fft1024<false>(v, b0, b1, j);
#pragma unroll
  for (int k = 0; k < 4; ++k) {
    int i = j + k * 256;
    double yv = -1.0 + 2.0 * (double)i / 1023.0;
    if (xj2 + yv * yv <= 0.25) v[k] = make_float2(0.0f, 0.0f);
  }
  fft1024<true>(v, b0, b1, j);
#pragma unroll
  for (int k = 0; k < 4; ++k) row[j + k * 256] = v[k];
}

// ---------------- inverse row FFT -> er (skipped cols compensated x1024) ----------------
__global__ void k_rowfft_inv(const float2* __restrict__ A, float* __restrict__ er) {
  __shared__ float2 b0[1088], b1[1088];
  int b = blockIdx.y, y = blockIdx.x, j = threadIdx.x;
  const float2* in = A + ((size_t)b * H + y) * W;
  float2 v[4];
#pragma unroll
  for (int k = 0; k < 4; ++k) v[k] = in[j + k * 256];
  v[0].x *= 1024.0f; v[0].y *= 1024.0f;
  v[3].x *= 1024.0f; v[3].y *= 1024.0f;
  fft1024<true>(v, b0, b1, j);
  float* out = er + ((size_t)b * H + y) * W;
#pragma unroll
  for (int k = 0; k < 4; ++k) out[j + k * 256] = v[k].x * FFT_SCALE;
}

// ---------------- Perona-Malik coefficients, packed half2 {cv, ch}, 4 px/thread ----------
__global__ void k_coeffs(const float* __restrict__ guide, const float* __restrict__ ybic,
                         const float* __restrict__ er, __half2* __restrict__ cvh) {
  int b = blockIdx.y, y = blockIdx.x, t = threadIdx.x;
  int x0 = t * 4;
  const float* g = guide + (size_t)b * 3 * H * W;
  const float* yb = ybic + (size_t)b * H * W;
  const float* e = er + (size_t)b * H * W;
  __half2* cp = cvh + (size_t)b * H * W;
  const size_t CH = (size_t)H * W;
  size_t row = (size_t)y * W + x0;
  float4 a0 = *(const float4*)(g + row);
  float4 a1 = *(const float4*)(g + CH + row);
  float4 a2 = *(const float4*)(g + 2 * CH + row);
  float4 a3 = *(const float4*)(yb + row);
  float4 e0 = *(const float4*)(e + row);
  float A0[5] = {a0.x, a0.y, a0.z, a0.w, 0.f};
  float A1[5] = {a1.x, a1.y, a1.z, a1.w, 0.f};
  float A2[5] = {a2.x, a2.y, a2.z, a2.w, 0.f};
  float A3[5] = {a3.x, a3.y, a3.z, a3.w, 0.f};
  float E0[5] = {e0.x, e0.y, e0.z, e0.w, 0.f};
  bool hasR = (x0 + 4 < W);
  if (hasR) {
    A0[4] = g[row + 4]; A1[4] = g[CH + row + 4]; A2[4] = g[2 * CH + row + 4];
    A3[4] = yb[row + 4]; E0[4] = e[row + 4];
  }
  float B0[4], B1[4], B2[4], B3[4], E1[4];
  bool hasD = (y < H - 1);
  if (hasD) {
    float4 q0 = *(const float4*)(g + row + W);
    float4 q1 = *(const float4*)(g + CH + row + W);
    float4 q2 = *(const float4*)(g + 2 * CH + row + W);
    float4 q3 = *(const float4*)(yb + row + W);
    float4 q4 = *(const float4*)(e + row + W);
    B0[0]=q0.x; B0[1]=q0.y; B0[2]=q0.z; B0[3]=q0.w;
    B1[0]=q1.x; B1[1]=q1.y; B1[2]=q1.z; B1[3]=q1.w;
    B2[0]=q2.x; B2[1]=q2.y; B2[2]=q2.z; B2[3]=q2.w;
    B3[0]=q3.x; B3[1]=q3.y; B3[2]=q3.z; B3[3]=q3.w;
    E1[0]=q4.x; E1[1]=q4.y; E1[2]=q4.z; E1[3]=q4.w;
  }
  __half2 outq[4];
#pragma unroll
  for (int i = 0; i < 4; ++i) {
    float cvv = 0.0f;
    if (hasD) {
      float s = fabsf(B0[i] - A0[i]) + fabsf(B1[i] - A1[i]) +
                fabsf(B2[i] - A2[i]) + fabsf(B3[i] - A3[i]);
      s = (s + E1[i]) * 0.25f;
      cvv = 1.0f / (1.0f + (s * s) / KK);
    }
    float chv = 0.0f;
    if (i < 3 || hasR) {
      float s = fabsf(A0[i + 1] - A0[i]) + fabsf(A1[i + 1] - A1[i]) +
                fabsf(A2[i + 1] - A2[i]) + fabsf(A3[i + 1] - A3[i]);
      s = (s + E0[i + 1]) * 0.25f;
      chv = 1.0f / (1.0f + (s * s) / KK);
    }
    outq[i] = __floats2half2_rn(cvv, chv);
  }
  *(float4*)(cp + row) = *(const float4*)outq;
}

// ================= cooperative persistent diffuse: all 8 iterations in one kernel ========
// 1024 blocks (4,64,4), 256 threads (32,8). Each block owns a 256x16 tile resident in LDS.
// Per iteration: compute acc, pool ratios; exchange boundary rows/cols + ratios through
// parity global buffers with threadfence + grid.sync (cross-XCD visibility).
// Coefficient halos are zeroed so image-edge terms vanish identically (matches k_coeffs zeros).
__global__ __launch_bounds__(256, 4) void k_diffuse_coop(
    const float* __restrict__ ybic, const __half2* __restrict__ cvh,
    const float* __restrict__ src, const float* __restrict__ mask,
    const unsigned* __restrict__ minp, float* __restrict__ ratA, float* __restrict__ ratB,
    float* __restrict__ halA, float* __restrict__ halB, float* __restrict__ out) {
  // LDS cols: interior 0..255 (aligned), 257 = left halo (x0-1), 258 = right halo (x0+256)
  __shared__ __half sImg[18][260];   // rows: 0 = y0-1 halo, 1..16 = tile, 17 = y0+16 halo
  __shared__ __half sCv[17][256];    // LAM*cv rows y0-1..y0+15 (row rr = y0-1+rr)
  __shared__ __half sCh[16][260];    // LAM*ch rows y0..y0+15; col 257 = x0-1 halo
  __shared__ float sSum[16][32];
  __shared__ float sRat[4][34];      // pool rows {above, A, B, below} x pool cols {-1,0..31,32}
  __shared__ float sSrcSh[2][32];
  __shared__ float sMaskUse[2][32];

  cg::grid_group grid = cg::this_grid();
  int bx = blockIdx.x, by = blockIdx.y, b = blockIdx.z;
  int tx = threadIdx.x, ty = threadIdx.y;
  int tid = ty * 32 + tx;
  int x0 = bx * 256, y0 = by * 16;
  float sh = shift_from_bits(minp);
  size_t base = (size_t)b * H * W;
  const float* yb = ybic + base;
  const __half2* cp = cvh + base;
  int blin = (b * 64 + by) * 4 + bx;

  // ---- preload (once) ----
  for (int tr = 0; tr < 16; ++tr)
    sImg[tr + 1][tid] = __float2half(yb[(size_t)(y0 + tr) * W + x0 + tid] + sh);
  sImg[0][tid] = (by > 0) ? __float2half(yb[(size_t)(y0 - 1) * W + x0 + tid] + sh)
                          : __float2half(0.f);
  sImg[17][tid] = (by < 63) ? __float2half(yb[(size_t)(y0 + 16) * W + x0 + tid] + sh)
                            : __float2half(0.f);
  if (tid < 16)
    sImg[1 + tid][257] = (bx > 0) ? __float2half(yb[(size_t)(y0 + tid) * W + x0 - 1] + sh)
                                  : __float2half(0.f);
  else if (tid < 32) {
    int rr = tid - 16;
    sImg[1 + rr][258] = (bx < 3) ? __float2half(yb[(size_t)(y0 + rr) * W + x0 + 256] + sh)
                                 : __float2half(0.f);
  }
  for (int rr = 0; rr < 17; ++rr) {
    int y = y0 - 1 + rr;
    float cvv = (y >= 0) ? __half2float(cp[(size_t)y * W + x0 + tid].x) * LAM : 0.f;
    sCv[rr][tid] = __float2half(cvv);
  }
  for (int tr = 0; tr < 16; ++tr)
    sCh[tr][tid] = __float2half(__half2float(cp[(size_t)(y0 + tr) * W + x0 + tid].y) * LAM);
  if (tid < 16)
    sCh[tid][257] = (bx > 0)
        ? __float2half(__half2float(cp[(size_t)(y0 + tid) * W + x0 - 1].y) * LAM)
        : __float2half(0.f);
  if (ty < 2) {
    int pr = 2 * by + ty, pc = bx * 32 + tx;
    size_t si = ((size_t)b * SH + pr) * SW + pc;
    sMaskUse[ty][tx] = (mask[si] < 0.5f) ? 0.f : 1.f;
    sSrcSh[ty][tx] = src[si] + sh;
  }
  if (tid < 4 * 34) ((float*)sRat)[tid] = 1.0f;
  __syncthreads();

  for (int it = 0; it < 8; ++it) {
    float acc[2][8];
#pragma unroll
    for (int hf = 0; hf < 2; ++hf) {
      int tr = ty + hf * 8;
      int r = tr + 1;
      int c0 = tx * 8;
      int prc = 1 + (tr >> 3);
      float rC = sRat[prc][1 + tx];
      float rU = (tr == 0) ? sRat[0][1 + tx] : sRat[1 + ((tr - 1) >> 3)][1 + tx];
      float rD = (tr == 15) ? sRat[3][1 + tx] : sRat[1 + ((tr + 1) >> 3)][1 + tx];
      float rL = (tx == 0) ? sRat[prc][0] : sRat[prc][tx];
      float rR = (tx == 31) ? sRat[prc][33] : sRat[prc][tx + 2];
      float C[8], U[8], D[8];
#pragma unroll
      for (int i = 0; i < 8; ++i) {
        C[i] = __half2float(sImg[r][c0 + i]) * rC;
        U[i] = __half2float(sImg[r - 1][c0 + i]) * rU;
        D[i] = __half2float(sImg[r + 1][c0 + i]) * rD;
      }
      float lf = ((tx == 0) ? __half2float(sImg[r][257]) : __half2float(sImg[r][c0 - 1])) * rL;
      float rt = ((tx == 31) ? __half2float(sImg[r][258]) : __half2float(sImg[r][c0 + 8])) * rR;
      float chl = (tx == 0) ? __half2float(sCh[tr][257]) : __half2float(sCh[tr][c0 - 1]);
      float s = 0.f;
#pragma unroll
      for (int i = 0; i < 8; ++i) {
        float cv_ = __half2float(sCv[tr + 1][c0 + i]);
        float cu_ = __half2float(sCv[tr][c0 + i]);
        float ch_ = __half2float(sCh[tr][c0 + i]);
        float cl_ = (i == 0) ? chl : __half2float(sCh[tr][c0 + i - 1]);
        float L = (i == 0) ? lf : C[i - 1];
        float R = (i == 7) ? rt : C[i + 1];
        float a = C[i] + cv_ * (D[i] - C[i]) - cu_ * (C[i] - U[i]) + ch_ * (R - C[i]) -
                  cl_ * (C[i] - L);
        acc[hf][i] = a;
        s += a;
      }
      sSum[tr][tx] = s;
    }
    __syncthreads();  // B1: sSum ready; all sImg/sRat reads done

    if (ty < 2) {
      float s = 0.f;
#pragma unroll
      for (int rr = 0; rr < 8; ++rr) s += sSum[ty * 8 + rr][tx];
      float mean = s * (1.0f / 64.0f);
      float rv = (sMaskUse[ty][tx] != 0.f) ? sSrcSh[ty][tx] / (mean + 1e-8f) : 1.f;
      sRat[1 + ty][1 + tx] = rv;
      if (it < 7) {
        int pr = 2 * by + ty, pc = bx * 32 + tx;
        float* rp = ((it & 1) ? ratB : ratA);
        rp[((size_t)b * SH + pr) * SW + pc] = rv;
      }
    }

    if (it == 7) {
      __syncthreads();
#pragma unroll
      for (int hf = 0; hf < 2; ++hf) {
        int tr = ty + hf * 8;
        float rv = sRat[1 + (tr >> 3)][1 + tx];
        float* op = out + base + (size_t)(y0 + tr) * W + x0 + tx * 8;
        *(float4*)op = make_float4(acc[hf][0] * rv - sh, acc[hf][1] * rv - sh,
                                   acc[hf][2] * rv - sh, acc[hf][3] * rv - sh);
        *(float4*)(op + 4) = make_float4(acc[hf][4] * rv - sh, acc[hf][5] * rv - sh,
                                         acc[hf][6] * rv - sh, acc[hf][7] * rv - sh);
      }
      return;
    }

    // store acc into LDS tile + export boundaries (raw, pre-ratio)
    float* hal = ((it & 1) ? halB : halA) + (size_t)blin * 576;
#pragma unroll
    for (int hf = 0; hf < 2; ++hf) {
      int tr = ty + hf * 8;
#pragma unroll
      for (int i = 0; i < 8; ++i) sImg[tr + 1][tx * 8 + i] = __float2half(acc[hf][i]);
      if (tr == 0) {
#pragma unroll
        for (int i = 0; i < 8; ++i) hal[tx * 8 + i] = acc[hf][i];
      }
      if (tr == 15) {
#pragma unroll
        for (int i = 0; i < 8; ++i) hal[256 + tx * 8 + i] = acc[hf][i];
      }
      if (tx == 0) hal[512 + tr] = acc[hf][0];
      if (tx == 31) hal[528 + tr] = acc[hf][7];
    }
    __threadfence();
    grid.sync();
    __threadfence();

    // import halos (same parity buffers; next iteration writes the other parity)
    {
      const float* rp = ((it & 1) ? ratB : ratA) + (size_t)b * SH * SW;
      int prA = 2 * by, prB = prA + 1;
      if (ty == 2) sRat[0][1 + tx] = (by > 0) ? rp[(size_t)(prA - 1) * SW + bx * 32 + tx] : 1.f;
      if (ty == 3) sRat[3][1 + tx] = (by < 63) ? rp[(size_t)(prB + 1) * SW + bx * 32 + tx] : 1.f;
      if (ty == 4 && tx < 4) {
        if (tx == 0) sRat[1][0] = (bx > 0) ? rp[(size_t)prA * SW + bx * 32 - 1] : 1.f;
        if (tx == 1) sRat[2][0] = (bx > 0) ? rp[(size_t)prB * SW + bx * 32 - 1] : 1.f;
        if (tx == 2) sRat[1][33] = (bx < 3) ? rp[(size_t)prA * SW + bx * 32 + 32] : 1.f;
        if (tx == 3) sRat[2][33] = (bx < 3) ? rp[(size_t)prB * SW + bx * 32 + 32] : 1.f;
      }
      const float* hb = ((it & 1) ? halB : halA);
      if (by > 0)
        sImg[0][tid] = __float2half(hb[(size_t)((b * 64 + by - 1) * 4 + bx) * 576 + 256 + tid]);
      if (by < 63)
        sImg[17][tid] = __float2half(hb[(size_t)((b * 64 + by + 1) * 4 + bx) * 576 + tid]);
      if (tid < 16 && bx > 0)
        sImg[1 + tid][257] = __float2half(hb[(size_t)((b * 64 + by) * 4 + bx - 1) * 576 + 528 + tid]);
      if (tid >= 16 && tid < 32 && bx < 3) {
        int rr = tid - 16;
        sImg[1 + rr][258] = __float2half(hb[(size_t)((b * 64 + by) * 4 + bx + 1) * 576 + 512 + rr]);
      }
    }
    __syncthreads();  // B3: imports visible
  }
}

// ---------------- fallback (R7) fused diffuse + ratio kernels ----------------
__device__ __forceinline__ void load8h(const __half* p, float o[8]) {
  float4 raw = *(const float4*)p;
  const __half2* h = (const __half2*)&raw;
#pragma unroll
  for (int i = 0; i < 4; ++i) {
    float2 f = __half22float2(h[i]);
    o[2 * i] = f.x; o[2 * i + 1] = f.y;
  }
}
__device__ __forceinline__ void load8f(const float* p, float o[8]) {
  float4 a = *(const float4*)p;
  float4 c = *(const float4*)(p + 4);
  o[0]=a.x; o[1]=a.y; o[2]=a.z; o[3]=a.w; o[4]=c.x; o[5]=c.y; o[6]=c.z; o[7]=c.w;
}
__device__ __forceinline__ void store8h(__half* p, const float o[8]) {
  float4 raw;
  __half2* h = (__half2*)&raw;
#pragma unroll
  for (int i = 0; i < 4; ++i) h[i] = __floats2half2_rn(o[2 * i], o[2 * i + 1]);
  *(float4*)p = raw;
}

template <bool FIRST, bool FINAL>
__global__ void k_diffuse_ratio(const float* __restrict__ inF, const __half* __restrict__ inH,
                                const float* __restrict__ ratio_in,
                                const unsigned* __restrict__ minp,
                                const __half2* __restrict__ cvh, const float* __restrict__ src,
                                const float* __restrict__ mask, float* __restrict__ outF,
                                __half* __restrict__ outH, float* __restrict__ ratio_out) {
  int b = blockIdx.z, tx = threadIdx.x, ty = threadIdx.y;
  int x0 = blockIdx.x * 256 + tx * 8;
  int y = blockIdx.y * 8 + ty;
  float sh = shift_from_bits(minp);
  float addv = FIRST ? sh : 0.0f;
  size_t base = (size_t)b * H * W;
  size_t row = (size_t)y * W + x0;
  bool hasU = (y > 0), hasD = (y < H - 1);
  bool hasL = (x0 > 0), hasR = (x0 + 8 < W);
  int px = x0 >> 3;
  float rq = 1.f, rup = 1.f, rdn = 1.f, rlf = 1.f, rrt = 1.f;
  if (!FIRST) {
    const float* rb = ratio_in + (size_t)b * SH * SW;
    int py = y >> 3;
    rq = rb[py * SW + px];
    rup = hasU ? rb[((y - 1) >> 3) * SW + px] : 1.f;
    rdn = hasD ? rb[((y + 1) >> 3) * SW + px] : 1.f;
    rlf = hasL ? rb[py * SW + (px - 1)] : 1.f;
    rrt = hasR ? rb[py * SW + (px + 1)] : 1.f;
  }
  float C[8], U[8] = {0}, D[8] = {0};
  float lf = 0.f, rt = 0.f;
  if (FIRST) {
    const float* I = inF + base;
    load8f(I + row, C);
    if (hasU) load8f(I + row - W, U);
    if (hasD) load8f(I + row + W, D);
    if (hasL) lf = I[row - 1];
    if (hasR) rt = I[row + 8];
  } else {
    const __half* I = inH + base;
    load8h(I + row, C);
    if (hasU) load8h(I + row - W, U);
    if (hasD) load8h(I + row + W, D);
    if (hasL) lf = __half2float(I[row - 1]);
    if (hasR) rt = __half2float(I[row + 8]);
  }
#pragma unroll
  for (int i = 0; i < 8; ++i) {
    C[i] = (C[i] + addv) * rq;
    U[i] = (U[i] + addv) * rup;
    D[i] = (D[i] + addv) * rdn;
  }
  lf = (lf + addv) * rlf;
  rt = (rt + addv) * rrt;
  const __half2* cp = cvh + base;
  float cvq[8], chq[8], cvu[8] = {0};
  {
    float4 r0 = *(const float4*)(cp + row);
    float4 r1 = *(const float4*)(cp + row + 4);
    const __half2* h0 = (const __half2*)&r0;
    const __half2* h1 = (const __half2*)&r1;
#pragma unroll
    for (int i = 0; i < 4; ++i) {
      float2 f = __half22float2(h0[i]); cvq[i] = f.x; chq[i] = f.y;
      float2 g = __half22float2(h1[i]); cvq[i + 4] = g.x; chq[i + 4] = g.y;
    }
    if (hasU) {
      float4 u0 = *(const float4*)(cp + row - W);
      float4 u1 = *(const float4*)(cp + row - W + 4);
      const __half2* p0 = (const __half2*)&u0;
      const __half2* p1 = (const __half2*)&u1;
#pragma unroll
      for (int i = 0; i < 4; ++i) {
        cvu[i] = __half2float(p0[i].x);
        cvu[i + 4] = __half2float(p1[i].x);
      }
    }
  }
  float chl = hasL ? __half2float(cp[row - 1].y) : 0.f;
  float acc[8];
#pragma unroll
  for (int i = 0; i < 8; ++i) {
    float L = (i == 0) ? lf : C[i - 1];
    float R = (i == 7) ? rt : C[i + 1];
    float cL = (i == 0) ? chl : chq[i - 1];
    float a = C[i];
    if (hasD) a += LAM * cvq[i] * (D[i] - C[i]);
    if (hasU) a -= LAM * cvu[i] * (C[i] - U[i]);
    if (i < 7 || hasR) a += LAM * chq[i] * (R - C[i]);
    if (i > 0 || hasL) a -= LAM * cL * (C[i] - L);
    acc[i] = a;
  }
  __shared__ float sd[8][32];
  __shared__ float rblk[32];
  sd[ty][tx] = acc[0] + acc[1] + acc[2] + acc[3] + acc[4] + acc[5] + acc[6] + acc[7];
  __syncthreads();
  if (ty == 0) {
    float s = 0.f;
#pragma unroll
    for (int r = 0; r < 8; ++r) s += sd[r][tx];
    size_t si = ((size_t)b * SH + blockIdx.y) * SW + (blockIdx.x * 32 + tx);
    float mean = s * (1.0f / 64.0f);
    float rv = (mask[si] < 0.5f) ? 1.0f : (src[si] + sh) / (mean + 1e-8f);
    if (FINAL) rblk[tx] = rv;
    else ratio_out[si] = rv;
  }
  if (FINAL) {
    __syncthreads();
    float rv = rblk[tx];
    float o[8];
#pragma unroll
    for (int i = 0; i < 8; ++i) o[i] = acc[i] * rv - sh;
    float* op = outF + base + row;
    *(float4*)op = make_float4(o[0], o[1], o[2], o[3]);
    *(float4*)(op + 4) = make_float4(o[4], o[5], o[6], o[7]);
  } else {
    store8h(outH + base + row, acc);
  }
}

}  // namespace

extern "C" void kernel_launch(void* const* d_in, const int* in_sizes, int n_in, void* d_out,
                              int out_size, void* d_ws, size_t ws_size, hipStream_t stream) {
  (void)in_sizes; (void)n_in; (void)out_size; (void)ws_size;
  const float* guide = (const float*)d_in[0];
  const float* source = (const float*)d_in[1];
  const float* mask = (const float*)d_in[2];
  const float* ybic = (const float*)d_in[3];
  float* out = (float*)d_out;

  char* ws = (char*)d_ws;
  float2* A = (float2*)ws;                                   // [0,32MB), dead after rowfft_inv
  float2* Bc = (float2*)(ws + (size_t)32 * 1024 * 1024);     // [32,48MB)
  float* er = (float*)(ws + (size_t)32 * 1024 * 1024);       // overlays Bc
  __half2* cvh = (__half2*)(ws + (size_t)48 * 1024 * 1024);  // [48,64MB)
  float* halA = (float*)ws;                                  // [0,4MB) overlays dead A
  float* halB = (float*)(ws + (size_t)4 * 1024 * 1024);      // [4,8MB)
  __half* hA = (__half*)(ws + (size_t)8 * 1024 * 1024);      // fallback ping [8,16MB)
  __half* hB = (__half*)(ws + (size_t)16 * 1024 * 1024);     // fallback pong [16,24MB)
  unsigned* minp = (unsigned*)(ws + (size_t)64 * 1024 * 1024);
  float* ratA = (float*)(ws + (size_t)64 * 1024 * 1024 + 4096);
  float* ratB = ratA + (size_t)NB * SH * SW;

  k_shift_min<<<64, 256, 0, stream>>>(source, minp);

  k_rowfft_fwd<<<dim3(H / 2, NB), 256, 0, stream>>>(guide, ybic, minp, A);
  dim3 gT(NCOL / 32, H / 32, NB), bT(32, 8);
  k_transpose_fwd<<<gT, bT, 0, stream>>>(A, Bc);
  k_colfft_mask<<<dim3(NCOL, NB), 256, 0, stream>>>(Bc);
  k_transpose_bwd<<<gT, bT, 0, stream>>>(Bc, A);
  k_rowfft_inv<<<dim3(H, NB), 256, 0, stream>>>(A, er);

  k_coeffs<<<dim3(H, NB), 256, 0, stream>>>(guide, ybic, er, cvh);

  // cooperative persistent diffuse (8 iterations, grid-synced)
  {
    const float* a_ybic = ybic;
    const __half2* a_cvh = cvh;
    const float* a_src = source;
    const float* a_mask = mask;
    const unsigned* a_minp = minp;
    float* a_ratA = ratA;
    float* a_ratB = ratB;
    float* a_halA = halA;
    float* a_halB = halB;
    float* a_out = out;
    void* args[] = {&a_ybic, &a_cvh, &a_src, &a_mask, &a_minp,
                    &a_ratA, &a_ratB, &a_halA, &a_halB, &a_out};
    hipError_t rc = hipLaunchCooperativeKernel((const void*)k_diffuse_coop, dim3(4, 64, 4),
                                               dim3(32, 8), args, 0, stream);
    if (rc != hipSuccess) {
      // fallback: R7's 8-kernel chain (identical math)
      dim3 gD(W / 256, H / 8, NB), bD(32, 8);
      k_diffuse_ratio<true, false><<<gD, bD, 0, stream>>>(ybic, nullptr, nullptr, minp, cvh,
                                                          source, mask, nullptr, hA, ratA);
      k_diffuse_ratio<false, false><<<gD, bD, 0, stream>>>(nullptr, hA, ratA, minp, cvh,
                                                           source, mask, nullptr, hB, ratB);
      k_diffuse_ratio<false, false><<<gD, bD, 0, stream>>>(nullptr, hB, ratB, minp, cvh,
                                                           source, mask, nullptr, hA, ratA);
      k_diffuse_ratio<false, false><<<gD, bD, 0, stream>>>(nullptr, hA, ratA, minp, cvh,
                                                           source, mask, nullptr, hB, ratB);
      k_diffuse_ratio<false, false><<<gD, bD, 0, stream>>>(nullptr, hB, ratB, minp, cvh,
                                                           source, mask, nullptr, hA, ratA);
      k_diffuse_ratio<false, false><<<gD, bD, 0, stream>>>(nullptr, hA, ratA, minp, cvh,
                                                           source, mask, nullptr, hB, ratB);
      k_diffuse_ratio<false, false><<<gD, bD, 0, stream>>>(nullptr, hB, ratB, minp, cvh,
                                                           source, mask, nullptr, hA, ratA);
      k_diffuse_ratio<false, true><<<gD, bD, 0, stream>>>(nullptr, hA, ratA, minp, cvh,
                                                          source, mask, out, nullptr, ratB);
    }
  }
}

// Round 9
// 307.324 us; speedup vs baseline: 6.9121x; 6.9121x over previous
//
#include <hip/hip_runtime.h>
#include <hip/hip_fp16.h>

namespace {

constexpr int H = 1024, W = 1024, NB = 4;
constexpr int SH = 128, SW = 128;
constexpr float LAM = 0.24f;
constexpr float KK = 0.03f * 0.03f;
constexpr float DEPS_V = 0.1f;
constexpr float FFT_SCALE = 1.0f / (1024.0f * 1024.0f);  // ortho fwd+inv combined
constexpr int COL_LO = 256, NCOL = 512;  // masked columns k2 in [256,768); margin ~1.5e-3

__device__ __forceinline__ float2 cadd(float2 a, float2 b) { return make_float2(a.x + b.x, a.y + b.y); }
__device__ __forceinline__ float2 csub(float2 a, float2 b) { return make_float2(a.x - b.x, a.y - b.y); }
__device__ __forceinline__ float2 cmul(float2 a, float2 b) {
  return make_float2(a.x * b.x - a.y * b.y, a.x * b.y + a.y * b.x);
}
__device__ __forceinline__ int phys2(int e) { return e + (e >> 4); }

__device__ __forceinline__ float shift_from_bits(const unsigned* minp) {
  float mn = __uint_as_float(minp[0]);
  return (mn <= DEPS_V) ? DEPS_V : 0.0f;
}

// ---------------- min(source) via device-scope atomicMin on uint bits ----------------
__global__ void k_shift_min(const float* __restrict__ src, unsigned* __restrict__ minp) {
  int t = threadIdx.x;
  int b0 = blockIdx.x * 1024;
  float m = fminf(fminf(src[b0 + t], src[b0 + t + 256]),
                  fminf(src[b0 + t + 512], src[b0 + t + 768]));
  for (int o = 32; o > 0; o >>= 1) m = fminf(m, __shfl_xor(m, o));
  __shared__ float sm[4];
  if ((t & 63) == 0) sm[t >> 6] = m;
  __syncthreads();
  if (t == 0) {
    float mm = fminf(fminf(sm[0], sm[1]), fminf(sm[2], sm[3]));
    atomicMin(minp, __float_as_uint(mm));
  }
}

// ---------------- Stockham radix-4 1024-pt FFT (natural in -> natural out) ----------------
template <int NS, bool INV>
__device__ __forceinline__ void r4_butterfly(float2 v[4], int j, float2 r[4]) {
  if (NS > 1) {
    int p = j & (NS - 1);
    float sn, cs;
    sincospif((INV ? 1.0f : -1.0f) * (float)p * (1.0f / (float)(2 * NS)), &sn, &cs);
    float2 w1 = make_float2(cs, sn);
    float2 w2 = cmul(w1, w1);
    float2 w3 = cmul(w2, w1);
    v[1] = cmul(v[1], w1);
    v[2] = cmul(v[2], w2);
    v[3] = cmul(v[3], w3);
  }
  float2 a0 = cadd(v[0], v[2]), a2 = csub(v[0], v[2]);
  float2 a1 = cadd(v[1], v[3]), a3 = csub(v[1], v[3]);
  a3 = INV ? make_float2(-a3.y, a3.x) : make_float2(a3.y, -a3.x);
  r[0] = cadd(a0, a1);
  r[2] = csub(a0, a1);
  r[1] = cadd(a2, a3);
  r[3] = csub(a2, a3);
}

template <int NS, bool INV>
__device__ __forceinline__ void r4_stage_lds(float2 v[4], float2* dst, int j) {
  float2 r[4];
  r4_butterfly<NS, INV>(v, j, r);
  int p = j & (NS - 1);
  int base = ((j - p) << 2) + p;
#pragma unroll
  for (int k = 0; k < 4; ++k) dst[phys2(base + k * NS)] = r[k];
}

__device__ __forceinline__ void lds_load4(const float2* src, float2 v[4], int j) {
#pragma unroll
  for (int k = 0; k < 4; ++k) v[k] = src[phys2(j + k * 256)];
}

template <bool INV>
__device__ void fft1024(float2 v[4], float2* b0, float2* b1, int j) {
  r4_stage_lds<1, INV>(v, b0, j);
  __syncthreads();
  lds_load4(b0, v, j);
  r4_stage_lds<4, INV>(v, b1, j);
  __syncthreads();
  lds_load4(b1, v, j);
  r4_stage_lds<16, INV>(v, b0, j);
  __syncthreads();
  lds_load4(b0, v, j);
  r4_stage_lds<64, INV>(v, b1, j);
  __syncthreads();
  lds_load4(b1, v, j);
  float2 r[4];
  r4_butterfly<256, INV>(v, j, r);
#pragma unroll
  for (int k = 0; k < 4; ++k) v[k] = r[k];
}

// ---------------- forward row FFT, 2 real rows packed per complex transform ----------------
__global__ void k_rowfft_fwd(const float* __restrict__ guide, const float* __restrict__ ybic,
                             const unsigned* __restrict__ minp, float2* __restrict__ A) {
  __shared__ float2 b0[1088], b1[1088];
  int b = blockIdx.y, y0 = blockIdx.x * 2, j = threadIdx.x;
  float sh = shift_from_bits(minp);
  const float* g0 = guide + ((size_t)(b * 3 + 0) * H + y0) * W;
  const float* g1 = guide + ((size_t)(b * 3 + 1) * H + y0) * W;
  const float* g2 = guide + ((size_t)(b * 3 + 2) * H + y0) * W;
  const float* yb = ybic + ((size_t)b * H + y0) * W;
  float2 v[4];
#pragma unroll
  for (int k = 0; k < 4; ++k) {
    int x = j + k * 256;
    float s0 = g0[x] + g1[x] + g2[x] + (yb[x] + sh);
    float s1 = g0[x + W] + g1[x + W] + g2[x + W] + (yb[x + W] + sh);
    v[k] = make_float2(s0, s1);
  }
  fft1024<false>(v, b0, b1, j);
#pragma unroll
  for (int k = 0; k < 4; ++k) b0[phys2(j + k * 256)] = v[k];
  __syncthreads();
  float2* o0 = A + ((size_t)b * H + y0) * W;
  float2* o1 = o0 + W;
#pragma unroll
  for (int k = 0; k < 4; ++k) {
    int m = j + k * 256;
    float2 Zm = v[k];
    float2 Zc = b0[phys2((1024 - m) & 1023)];
    o0[m] = make_float2(0.5f * (Zm.x + Zc.x), 0.5f * (Zm.y - Zc.y));
    o1[m] = make_float2(0.5f * (Zm.y + Zc.y), 0.5f * (Zc.x - Zm.x));
  }
}

// ---------------- half-width transposes ----------------
__global__ void k_transpose_fwd(const float2* __restrict__ A, float2* __restrict__ Bc) {
  __shared__ float2 tile[32][33];
  int b = blockIdx.z;
  int c0 = blockIdx.x * 32, y0 = blockIdx.y * 32;
  const float2* ip = A + (size_t)b * H * W;
  float2* op = Bc + (size_t)b * NCOL * H;
#pragma unroll
  for (int k = 0; k < 4; ++k)
    tile[threadIdx.y + k * 8][threadIdx.x] =
        ip[(size_t)(y0 + threadIdx.y + k * 8) * W + (COL_LO + c0 + threadIdx.x)];
  __syncthreads();
#pragma unroll
  for (int k = 0; k < 4; ++k)
    op[(size_t)(c0 + threadIdx.y + k * 8) * H + (y0 + threadIdx.x)] =
        tile[threadIdx.x][threadIdx.y + k * 8];
}

__global__ void k_transpose_bwd(const float2* __restrict__ Bc, float2* __restrict__ A) {
  __shared__ float2 tile[32][33];
  int b = blockIdx.z;
  int c0 = blockIdx.x * 32, y0 = blockIdx.y * 32;
  const float2* ip = Bc + (size_t)b * NCOL * H;
  float2* op = A + (size_t)b * H * W;
#pragma unroll
  for (int k = 0; k < 4; ++k)
    tile[threadIdx.y + k * 8][threadIdx.x] =
        ip[(size_t)(c0 + threadIdx.y + k * 8) * H + (y0 + threadIdx.x)];
  __syncthreads();
#pragma unroll
  for (int k = 0; k < 4; ++k)
    op[(size_t)(y0 + threadIdx.y + k * 8) * W + (COL_LO + c0 + threadIdx.x)] =
        tile[threadIdx.x][threadIdx.y + k * 8];
}

// ---------------- column FFT + radial mask + inverse column FFT ----------------
__global__ void k_colfft_mask(float2* __restrict__ Bc) {
  __shared__ float2 b0[1088], b1[1088];
  int b = blockIdx.y, r = blockIdx.x, j = threadIdx.x;
  int k2 = COL_LO + r;
  double xj = -1.0 + 2.0 * (double)k2 / 1023.0;
  double xj2 = xj * xj;
  float2* row = Bc + ((size_t)b * NCOL + r) * H;
  float2 v[4];
#pragma unroll
  for (int k = 0; k < 4; ++k) v[k] = row[j + k * 256];
  fft1024<false>(v, b0, b1, j);
#pragma unroll
  for (int k = 0; k < 4; ++k) {
    int i = j + k * 256;
    double yv = -1.0 + 2.0 * (double)i / 1023.0;
    if (xj2 + yv * yv <= 0.25) v[k] = make_float2(0.0f, 0.0f);
  }
  fft1024<true>(v, b0, b1, j);
#pragma unroll
  for (int k = 0; k < 4; ++k) row[j + k * 256] = v[k];
}

// ---------------- inverse row FFT -> er (skipped cols compensated x1024) ----------------
__global__ void k_rowfft_inv(const float2* __restrict__ A, float* __restrict__ er) {
  __shared__ float2 b0[1088], b1[1088];
  int b = blockIdx.y, y = blockIdx.x, j = threadIdx.x;
  const float2* in = A + ((size_t)b * H + y) * W;
  float2 v[4];
#pragma unroll
  for (int k = 0; k < 4; ++k) v[k] = in[j + k * 256];
  v[0].x *= 1024.0f; v[0].y *= 1024.0f;
  v[3].x *= 1024.0f; v[3].y *= 1024.0f;
  fft1024<true>(v, b0, b1, j);
  float* out = er + ((size_t)b * H + y) * W;
#pragma unroll
  for (int k = 0; k < 4; ++k) out[j + k * 256] = v[k].x * FFT_SCALE;
}

// ---------------- Perona-Malik coefficients, packed half2 {LAM*cv, LAM*ch} ----------
__global__ void k_coeffs(const float* __restrict__ guide, const float* __restrict__ ybic,
                         const float* __restrict__ er, __half2* __restrict__ cvh) {
  int b = blockIdx.y, y = blockIdx.x, t = threadIdx.x;
  int x0 = t * 4;
  const float* g = guide + (size_t)b * 3 * H * W;
  const float* yb = ybic + (size_t)b * H * W;
  const float* e = er + (size_t)b * H * W;
  __half2* cp = cvh + (size_t)b * H * W;
  const size_t CH = (size_t)H * W;
  size_t row = (size_t)y * W + x0;
  float4 a0 = *(const float4*)(g + row);
  float4 a1 = *(const float4*)(g + CH + row);
  float4 a2 = *(const float4*)(g + 2 * CH + row);
  float4 a3 = *(const float4*)(yb + row);
  float4 e0 = *(const float4*)(e + row);
  float A0[5] = {a0.x, a0.y, a0.z, a0.w, 0.f};
  float A1[5] = {a1.x, a1.y, a1.z, a1.w, 0.f};
  float A2[5] = {a2.x, a2.y, a2.z, a2.w, 0.f};
  float A3[5] = {a3.x, a3.y, a3.z, a3.w, 0.f};
  float E0[5] = {e0.x, e0.y, e0.z, e0.w, 0.f};
  bool hasR = (x0 + 4 < W);
  if (hasR) {
    A0[4] = g[row + 4]; A1[4] = g[CH + row + 4]; A2[4] = g[2 * CH + row + 4];
    A3[4] = yb[row + 4]; E0[4] = e[row + 4];
  }
  float B0[4], B1[4], B2[4], B3[4], E1[4];
  bool hasD = (y < H - 1);
  if (hasD) {
    float4 q0 = *(const float4*)(g + row + W);
    float4 q1 = *(const float4*)(g + CH + row + W);
    float4 q2 = *(const float4*)(g + 2 * CH + row + W);
    float4 q3 = *(const float4*)(yb + row + W);
    float4 q4 = *(const float4*)(e + row + W);
    B0[0]=q0.x; B0[1]=q0.y; B0[2]=q0.z; B0[3]=q0.w;
    B1[0]=q1.x; B1[1]=q1.y; B1[2]=q1.z; B1[3]=q1.w;
    B2[0]=q2.x; B2[1]=q2.y; B2[2]=q2.z; B2[3]=q2.w;
    B3[0]=q3.x; B3[1]=q3.y; B3[2]=q3.z; B3[3]=q3.w;
    E1[0]=q4.x; E1[1]=q4.y; E1[2]=q4.z; E1[3]=q4.w;
  }
  __half2 outq[4];
#pragma unroll
  for (int i = 0; i < 4; ++i) {
    float cvv = 0.0f;
    if (hasD) {
      float s = fabsf(B0[i] - A0[i]) + fabsf(B1[i] - A1[i]) +
                fabsf(B2[i] - A2[i]) + fabsf(B3[i] - A3[i]);
      s = (s + E1[i]) * 0.25f;
      cvv = LAM / (1.0f + (s * s) / KK);   // LAM baked in
    }
    float chv = 0.0f;
    if (i < 3 || hasR) {
      float s = fabsf(A0[i + 1] - A0[i]) + fabsf(A1[i + 1] - A1[i]) +
                fabsf(A2[i + 1] - A2[i]) + fabsf(A3[i + 1] - A3[i]);
      s = (s + E0[i + 1]) * 0.25f;
      chv = LAM / (1.0f + (s * s) / KK);   // LAM baked in
    }
    outq[i] = __floats2half2_rn(cvv, chv);
  }
  *(float4*)(cp + row) = *(const float4*)outq;
}

// ---------------- helpers: 8-px fp16 LDS load/store (16B aligned) ----------------
__device__ __forceinline__ void ld8(const __half* p, int c0, float o[8]) {
  float4 raw = *(const float4*)(p + c0);
  const __half2* h = (const __half2*)&raw;
#pragma unroll
  for (int i = 0; i < 4; ++i) {
    float2 f = __half22float2(h[i]);
    o[2 * i] = f.x; o[2 * i + 1] = f.y;
  }
}
__device__ __forceinline__ void st8(__half* p, int c0, const float v[8]) {
  float4 raw;
  __half2* h = (__half2*)&raw;
#pragma unroll
  for (int i = 0; i < 4; ++i) h[i] = __floats2half2_rn(v[2 * i], v[2 * i + 1]);
  *(float4*)(p + c0) = raw;
}

// ================= pair-fused diffuse: 2 iterations per kernel, block-local only ==========
// Tile T = 256x16 at (x0,y0). EXT region rows y0-9..y0+24 (e in [0,34)), cols x0-16..x0+271
// (octet o in [0,36), c = 8o). REGA (iter-A stencil) = EXT rows e 1..32, octets 1..34.
// Halo arithmetic: iter-B on T needs r^A on pools of T+1-ring -> acc^A on those full pools
// (rows y0-8..y0+23, cols x0-8..x0+263) -> img^A on +1 ring = EXT. Coefficient zeros at
// image edges make out-of-image terms vanish (same semantics as the verified R4-R7 chain).
template <bool FIRST, bool LAST>
__global__ __launch_bounds__(256, 2) void k_diffuse_pair(
    const float* __restrict__ ybic, const __half* __restrict__ imgIn,
    const float* __restrict__ ratio_in, const unsigned* __restrict__ minp,
    const __half2* __restrict__ cvh, const float* __restrict__ src,
    const float* __restrict__ mask, __half* __restrict__ imgOut,
    float* __restrict__ ratio_out, float* __restrict__ out) {
  __shared__ __align__(16) __half sImg[34 * 288];
  __shared__ __align__(16) __half sCv[33 * 288];
  __shared__ __align__(16) __half sCh[32 * 288];
  __shared__ __align__(16) __half sAcc[32 * 288];
  __shared__ float sSum[32][34];
  __shared__ float sRatA[4][34];
  __shared__ float sRatB[2][32];
  __shared__ float sRin[6][36];

  int bx = blockIdx.x, by = blockIdx.y, b = blockIdx.z;
  int tx = threadIdx.x, ty = threadIdx.y;
  int tid = ty * 32 + tx;
  int x0 = bx * 256, y0 = by * 16;
  float sh = shift_from_bits(minp);
  size_t base = (size_t)b * H * W;

  // Phase 0: incoming ratio window (pools 2by-2..2by+3 x 32bx-2..32bx+33)
  if (!FIRST) {
    if (tid < 216) {
      int pr = tid / 36, pc = tid % 36;
      int prg = 2 * by - 2 + pr, pcg = 32 * bx - 2 + pc;
      float rv = 1.f;
      if (prg >= 0 && prg < SH && pcg >= 0 && pcg < SW)
        rv = ratio_in[((size_t)b * SH + prg) * SW + pcg];
      sRin[pr][pc] = rv;
    }
    __syncthreads();
  }

  // Phase 1: load img^A (= in*r_prev (+sh if FIRST)) and LAM-scaled coefficients into LDS.
  for (int e = ty; e < 34; e += 8) {
    int yg = y0 - 9 + e;
    bool yok = (yg >= 0 && yg < H);
    for (int o = tx; o < 36; o += 32) {
      int colg = x0 - 16 + 8 * o;
      bool xok = (colg >= 0 && colg + 7 < W);
      int c0 = 8 * o;
      float4 packed = make_float4(0.f, 0.f, 0.f, 0.f);
      if (yok && xok) {
        if (FIRST) {
          const float* p = ybic + base + (size_t)yg * W + colg;
          float4 a = *(const float4*)p, c = *(const float4*)(p + 4);
          __half2* hh = (__half2*)&packed;
          hh[0] = __floats2half2_rn(a.x + sh, a.y + sh);
          hh[1] = __floats2half2_rn(a.z + sh, a.w + sh);
          hh[2] = __floats2half2_rn(c.x + sh, c.y + sh);
          hh[3] = __floats2half2_rn(c.z + sh, c.w + sh);
        } else {
          float4 raw = *(const float4*)(imgIn + base + (size_t)yg * W + colg);
          float r = sRin[((7 + e) >> 3)][o];  // pool-row rel = (yg+16)>>3 - 2by = (7+e)>>3
          const __half2* hh = (const __half2*)&raw;
          __half2* po = (__half2*)&packed;
#pragma unroll
          for (int i = 0; i < 4; ++i) {
            float2 f = __half22float2(hh[i]);
            po[i] = __floats2half2_rn(f.x * r, f.y * r);
          }
        }
      }
      *(float4*)&sImg[e * 288 + c0] = packed;
      // coefficients
      float4 cp0 = make_float4(0.f, 0.f, 0.f, 0.f), cp1 = cp0;
      if (yok && xok) {
        const __half2* p = cvh + base + (size_t)yg * W + colg;
        cp0 = *(const float4*)p;
        cp1 = *(const float4*)(p + 4);
      }
      __half cvs[8], chs[8];
      const __half2* q0 = (const __half2*)&cp0;
      const __half2* q1 = (const __half2*)&cp1;
#pragma unroll
      for (int i = 0; i < 4; ++i) {
        cvs[i] = q0[i].x; chs[i] = q0[i].y;
        cvs[4 + i] = q1[i].x; chs[4 + i] = q1[i].y;
      }
      if (e < 33) *(float4*)&sCv[e * 288 + c0] = *(const float4*)cvs;
      if (e >= 1) *(float4*)&sCh[(e - 1) * 288 + c0] = *(const float4*)chs;
    }
  }
  __syncthreads();

  // Phase 2: acc^A over REGA (rows em 0..31 = y0-8.., octets 1..34)
  for (int rg = 0; rg < 4; ++rg) {
    int em = rg * 8 + ty;
    int e = em + 1;
    const __half* rowC = &sImg[e * 288];
    const __half* rowU = &sImg[(e - 1) * 288];
    const __half* rowD = &sImg[(e + 1) * 288];
    const __half* cvC = &sCv[e * 288];
    const __half* cvU = &sCv[(e - 1) * 288];
    const __half* chC = &sCh[em * 288];
    for (int o = 1 + tx; o < 35; o += 32) {
      int c0 = 8 * o;
      float C[8], U[8], D[8], cvd[8], cvu[8], chr[8];
      ld8(rowC, c0, C); ld8(rowU, c0, U); ld8(rowD, c0, D);
      ld8(cvC, c0, cvd); ld8(cvU, c0, cvu); ld8(chC, c0, chr);
      float L = __half2float(rowC[c0 - 1]);
      float R = __half2float(rowC[c0 + 8]);
      float chl = __half2float(chC[c0 - 1]);
      float acc[8], s = 0.f;
#pragma unroll
      for (int i = 0; i < 8; ++i) {
        float l = (i == 0) ? L : C[i - 1];
        float r = (i == 7) ? R : C[i + 1];
        float cl = (i == 0) ? chl : chr[i - 1];
        float a = C[i] + cvd[i] * (D[i] - C[i]) - cvu[i] * (C[i] - U[i]) +
                  chr[i] * (r - C[i]) - cl * (C[i] - l);
        acc[i] = a;
        s += a;
      }
      st8(&sAcc[em * 288], c0, acc);
      sSum[em][o - 1] = s;
    }
  }
  __syncthreads();

  // Phase 2b: r^A for pools 2by-1..2by+2 x 32bx-1..32bx+32
  if (tid < 136) {
    int pr = tid / 34, pc = tid % 34;
    float s = 0.f;
#pragma unroll
    for (int r = 0; r < 8; ++r) s += sSum[pr * 8 + r][pc];
    int prg = 2 * by - 1 + pr, pcg = 32 * bx - 1 + pc;
    float rv = 1.f;
    if (prg >= 0 && prg < SH && pcg >= 0 && pcg < SW) {
      size_t si = ((size_t)b * SH + prg) * SW + pcg;
      if (mask[si] >= 0.5f) rv = (src[si] + sh) / (s * (1.0f / 64.0f) + 1e-8f);
    }
    sRatA[pr][pc] = rv;
  }
  __syncthreads();

  // Phase 3: acc^B over T (img^B = acc^A * r^A applied on read)
  float accB[2][8];
#pragma unroll
  for (int hf = 0; hf < 2; ++hf) {
    int tr = hf * 8 + ty;      // T row 0..15
    int em = tr + 8, e = em + 1;
    int o = 2 + tx, c0 = 8 * o;
    const __half* rowC = &sAcc[em * 288];
    const __half* rowU = &sAcc[(em - 1) * 288];
    const __half* rowD = &sAcc[(em + 1) * 288];
    const __half* cvC = &sCv[e * 288];
    const __half* cvU = &sCv[(e - 1) * 288];
    const __half* chC = &sCh[em * 288];
    float rC = sRatA[1 + (tr >> 3)][1 + tx];
    float rU = sRatA[(tr + 7) >> 3][1 + tx];
    float rDn = sRatA[((tr + 1) >> 3) + 1][1 + tx];
    float rL = sRatA[1 + (tr >> 3)][tx];
    float rR = sRatA[1 + (tr >> 3)][tx + 2];
    float C[8], U[8], D[8], cvd[8], cvu[8], chr[8];
    ld8(rowC, c0, C); ld8(rowU, c0, U); ld8(rowD, c0, D);
    ld8(cvC, c0, cvd); ld8(cvU, c0, cvu); ld8(chC, c0, chr);
#pragma unroll
    for (int i = 0; i < 8; ++i) { C[i] *= rC; U[i] *= rU; D[i] *= rDn; }
    float L = __half2float(rowC[c0 - 1]) * rL;
    float R = __half2float(rowC[c0 + 8]) * rR;
    float chl = __half2float(chC[c0 - 1]);
    float s = 0.f;
#pragma unroll
    for (int i = 0; i < 8; ++i) {
      float l = (i == 0) ? L : C[i - 1];
      float r = (i == 7) ? R : C[i + 1];
      float cl = (i == 0) ? chl : chr[i - 1];
      float a = C[i] + cvd[i] * (D[i] - C[i]) - cvu[i] * (C[i] - U[i]) +
                chr[i] * (r - C[i]) - cl * (C[i] - l);
      accB[hf][i] = a;
      s += a;
    }
    sSum[tr][tx] = s;
  }
  __syncthreads();

  // Phase 3b: r^B for T's own pools (2 x 32); export for next pair.
  if (tid < 64) {
    int pr = tid >> 5, pc = tid & 31;
    float s = 0.f;
#pragma unroll
    for (int r = 0; r < 8; ++r) s += sSum[pr * 8 + r][pc];
    size_t si = ((size_t)b * SH + 2 * by + pr) * SW + (32 * bx + pc);
    float rv = (mask[si] < 0.5f) ? 1.f : (src[si] + sh) / (s * (1.0f / 64.0f) + 1e-8f);
    sRatB[pr][pc] = rv;
    if (!LAST) ratio_out[si] = rv;
  }
  if (LAST) __syncthreads();

  // Phase 4: write acc^B (raw fp16 for next pair; or *r^B - sh f32 for final output)
#pragma unroll
  for (int hf = 0; hf < 2; ++hf) {
    int tr = hf * 8 + ty;
    int yg = y0 + tr, colg = x0 + 8 * tx;
    if (LAST) {
      float rv = sRatB[tr >> 3][tx];
      float* op = out + base + (size_t)yg * W + colg;
      *(float4*)op = make_float4(accB[hf][0] * rv - sh, accB[hf][1] * rv - sh,
                                 accB[hf][2] * rv - sh, accB[hf][3] * rv - sh);
      *(float4*)(op + 4) = make_float4(accB[hf][4] * rv - sh, accB[hf][5] * rv - sh,
                                       accB[hf][6] * rv - sh, accB[hf][7] * rv - sh);
    } else {
      st8(imgOut + base + (size_t)yg * W, colg, accB[hf]);
    }
  }
}

}  // namespace

extern "C" void kernel_launch(void* const* d_in, const int* in_sizes, int n_in, void* d_out,
                              int out_size, void* d_ws, size_t ws_size, hipStream_t stream) {
  (void)in_sizes; (void)n_in; (void)out_size; (void)ws_size;
  const float* guide = (const float*)d_in[0];
  const float* source = (const float*)d_in[1];
  const float* mask = (const float*)d_in[2];
  const float* ybic = (const float*)d_in[3];
  float* out = (float*)d_out;

  char* ws = (char*)d_ws;
  float2* A = (float2*)ws;                                   // [0,32MB), dead after rowfft_inv
  float2* Bc = (float2*)(ws + (size_t)32 * 1024 * 1024);     // [32,48MB)
  float* er = (float*)(ws + (size_t)32 * 1024 * 1024);       // overlays Bc
  __half2* cvh = (__half2*)(ws + (size_t)48 * 1024 * 1024);  // [48,64MB)
  __half* hA = (__half*)(ws + (size_t)8 * 1024 * 1024);      // [8,16MB) overlays dead A
  __half* hB = (__half*)(ws + (size_t)16 * 1024 * 1024);     // [16,24MB)
  unsigned* minp = (unsigned*)(ws + (size_t)64 * 1024 * 1024);
  float* ratA = (float*)(ws + (size_t)64 * 1024 * 1024 + 4096);
  float* ratB = ratA + (size_t)NB * SH * SW;

  k_shift_min<<<64, 256, 0, stream>>>(source, minp);

  k_rowfft_fwd<<<dim3(H / 2, NB), 256, 0, stream>>>(guide, ybic, minp, A);
  dim3 gT(NCOL / 32, H / 32, NB), bT(32, 8);
  k_transpose_fwd<<<gT, bT, 0, stream>>>(A, Bc);
  k_colfft_mask<<<dim3(NCOL, NB), 256, 0, stream>>>(Bc);
  k_transpose_bwd<<<gT, bT, 0, stream>>>(Bc, A);
  k_rowfft_inv<<<dim3(H, NB), 256, 0, stream>>>(A, er);

  k_coeffs<<<dim3(H, NB), 256, 0, stream>>>(guide, ybic, er, cvh);

  // 4 pair-fused diffuse kernels = 8 iterations (iters {0,1},{2,3},{4,5},{6,7})
  dim3 gP(4, 64, NB), bP(32, 8);
  k_diffuse_pair<true, false><<<gP, bP, 0, stream>>>(ybic, nullptr, nullptr, minp, cvh,
                                                     source, mask, hA, ratA, nullptr);
  k_diffuse_pair<false, false><<<gP, bP, 0, stream>>>(nullptr, hA, ratA, minp, cvh,
                                                      source, mask, hB, ratB, nullptr);
  k_diffuse_pair<false, false><<<gP, bP, 0, stream>>>(nullptr, hB, ratB, minp, cvh,
                                                      source, mask, hA, ratA, nullptr);
  k_diffuse_pair<false, true><<<gP, bP, 0, stream>>>(nullptr, hA, ratA, minp, cvh,
                                                     source, mask, nullptr, nullptr, out);
}